// Round 12
// baseline (391.030 us; speedup 1.0000x reference)
//
#include <hip/hip_runtime.h>
#include <hip/hip_bf16.h>

#define L_ 1024
#define BH_ 64
#define NEGV (-1e15f)
#define QSCALE 0.18033688011112043f   // log2(e)/8: exp(S/8) == exp2(S*QSCALE)

typedef float f32x4 __attribute__((ext_vector_type(4)));
typedef short s16x8 __attribute__((ext_vector_type(8)));
typedef unsigned short ushort_t;

__device__ __forceinline__ unsigned short f2bf(float f) {
    return __builtin_bit_cast(unsigned short, __float2bfloat16(f));
}
__device__ __forceinline__ unsigned selw(uint4 v, int i) {
    switch (i) { case 0: return v.x; case 1: return v.y; case 2: return v.z; default: return v.w; }
}
__device__ __forceinline__ unsigned spread4(unsigned n) {   // bit j -> bit 4j
    return (n & 1u) | ((n & 2u) << 3) | ((n & 4u) << 6) | ((n & 8u) << 9);
}
__device__ __forceinline__ unsigned pack_bytes_nz(uint4 m) {
    unsigned u = 0;
    #pragma unroll
    for (int k = 0; k < 4; ++k) {
        const unsigned x = selw(m, k);
        u |= ((x & 0x000000FFu) ? 1u : 0u) << (k * 4 + 0);
        u |= ((x & 0x0000FF00u) ? 1u : 0u) << (k * 4 + 1);
        u |= ((x & 0x00FF0000u) ? 1u : 0u) << (k * 4 + 2);
        u |= ((x & 0xFF000000u) ? 1u : 0u) << (k * 4 + 3);
    }
    return u;
}

// 16-ballot transpose: row of 1024 i32 -> this lane's 16-col bit word.
template<bool TESTZERO>
__device__ __forceinline__ unsigned row_bits_i32(uint4 e0, uint4 e1, uint4 e2, uint4 e3, int ln)
{
    #define BAL_(v) (TESTZERO ? __ballot((v) == 0u) : __ballot((v) != 0u))
    const unsigned long long b00 = BAL_(e0.x), b01 = BAL_(e0.y), b02 = BAL_(e0.z), b03 = BAL_(e0.w);
    const unsigned long long b10 = BAL_(e1.x), b11 = BAL_(e1.y), b12 = BAL_(e1.z), b13 = BAL_(e1.w);
    const unsigned long long b20 = BAL_(e2.x), b21 = BAL_(e2.y), b22 = BAL_(e2.z), b23 = BAL_(e2.w);
    const unsigned long long b30 = BAL_(e3.x), b31 = BAL_(e3.y), b32 = BAL_(e3.z), b33 = BAL_(e3.w);
    #undef BAL_
    const int q0 = ln >> 4, sh = (ln & 15) << 2;
    unsigned u = 0;
    unsigned long long bp;
    bp = q0 == 0 ? b00 : q0 == 1 ? b10 : q0 == 2 ? b20 : b30;
    u |= spread4((unsigned)((bp >> sh) & 0xF)) << 0;
    bp = q0 == 0 ? b01 : q0 == 1 ? b11 : q0 == 2 ? b21 : b31;
    u |= spread4((unsigned)((bp >> sh) & 0xF)) << 1;
    bp = q0 == 0 ? b02 : q0 == 1 ? b12 : q0 == 2 ? b22 : b32;
    u |= spread4((unsigned)((bp >> sh) & 0xF)) << 2;
    bp = q0 == 0 ? b03 : q0 == 1 ? b13 : q0 == 2 ? b23 : b33;
    u |= spread4((unsigned)((bp >> sh) & 0xF)) << 3;
    return u;
}

// ws layout (ushort units): K' [0,4M), V' [4M,8M), Q' [8M,12M), mb [12M,16M)
__global__ __launch_bounds__(256)
void prep(const float* __restrict__ qp, const float* __restrict__ kp,
          const float* __restrict__ vp, const unsigned char* __restrict__ maskp,
          const int* __restrict__ edgep, ushort_t* __restrict__ ws)
{
    __shared__ float tile[128][68];
    ushort_t* Kp = ws;
    ushort_t* Vp = ws + (1u << 22);
    ushort_t* Qp = ws + (2u << 22);
    ushort_t* Mp = ws + (3u << 22);

    const int b = blockIdx.x;
    const int t = threadIdx.x;

    if (b < 512) {
        // ---- K' ----
        const int bh = b >> 3, kt = b & 7;
        const int r = t >> 1, h = t & 1;
        const float* src = kp + (((size_t)((bh << 10) + (kt << 7) + r)) << 6) + (h << 5);
        float v[32];
        #pragma unroll
        for (int j = 0; j < 8; ++j) *(float4*)&v[j << 2] = *((const float4*)src + j);
        ushort_t* dst = Kp + ((size_t)((bh << 3) + kt) << 13) + (r << 6);
        #pragma unroll
        for (int q = 0; q < 4; ++q) {
            const int c = (h << 2) + q;
            const int s = c ^ (r & 7);
            s16x8 o;
            #pragma unroll
            for (int j = 0; j < 8; ++j) o[j] = (short)f2bf(v[(q << 3) + j]);
            *(s16x8*)(dst + (s << 3)) = o;
        }
    } else if (b < 1024) {
        // ---- V' (LDS-tiled transpose, both sides coalesced) ----
        const int idx = b - 512;
        const int bh = idx >> 3, vt = idx & 7;
        const float* vsrc = vp + (((size_t)(bh << 10) + (vt << 7)) << 6);
        #pragma unroll
        for (int i = 0; i < 8; ++i) {
            const int f4 = (i << 8) + t;
            const int k = f4 >> 4, d4 = f4 & 15;
            *(float4*)&tile[k][d4 << 2] = *((const float4*)vsrc + f4);
        }
        __syncthreads();
        ushort_t* dst = Vp + ((size_t)((bh << 3) + vt) << 13);
        #pragma unroll
        for (int i = 0; i < 4; ++i) {
            const int ci = (t << 2) + i;
            const int d = ci >> 4, p = ci & 15;
            const int c = p ^ (d & 7);
            s16x8 o;
            #pragma unroll
            for (int j = 0; j < 8; ++j) o[j] = (short)f2bf(tile[(c << 3) + j][d]);
            *(s16x8*)(dst + (ci << 3)) = o;
        }
    } else if (b < 1088) {
        // ---- Q' ----
        const int bh = b - 1024;
        const int wv = t >> 6, ln = t & 63;
        for (int i = 0; i < 16; ++i) {
            const int rt = (i << 2) + wv;
            const int r = (rt << 4) + (ln & 15), gq = ln >> 4;
            const float* src = qp + (((size_t)((bh << 10) + r)) << 6) + (gq << 3);
            const float4 q0 = *(const float4*)src;
            const float4 q1 = *(const float4*)(src + 4);
            const float4 q2 = *(const float4*)(src + 32);
            const float4 q3 = *(const float4*)(src + 36);
            s16x8 a, bfr;
            a[0]=(short)f2bf(q0.x*QSCALE); a[1]=(short)f2bf(q0.y*QSCALE);
            a[2]=(short)f2bf(q0.z*QSCALE); a[3]=(short)f2bf(q0.w*QSCALE);
            a[4]=(short)f2bf(q1.x*QSCALE); a[5]=(short)f2bf(q1.y*QSCALE);
            a[6]=(short)f2bf(q1.z*QSCALE); a[7]=(short)f2bf(q1.w*QSCALE);
            bfr[0]=(short)f2bf(q2.x*QSCALE); bfr[1]=(short)f2bf(q2.y*QSCALE);
            bfr[2]=(short)f2bf(q2.z*QSCALE); bfr[3]=(short)f2bf(q2.w*QSCALE);
            bfr[4]=(short)f2bf(q3.x*QSCALE); bfr[5]=(short)f2bf(q3.y*QSCALE);
            bfr[6]=(short)f2bf(q3.z*QSCALE); bfr[7]=(short)f2bf(q3.w*QSCALE);
            ushort_t* dst = Qp + ((size_t)((bh << 6) + rt) << 10) + (ln << 4);
            *(s16x8*)(dst) = a;
            *(s16x8*)(dst + 8) = bfr;
        }
    } else {
        // ---- mb: edge ballot once, OR mask bits per bh, single write ----
        const int wv = t >> 6, ln = t & 63;
        const int rid = ((b - 1088) << 2) + wv;   // 0..4095
        const int eb = rid >> 10, row = rid & 1023;

        unsigned det = 0;
        const unsigned* mu = (const unsigned*)maskp;
        #pragma unroll
        for (int i = 0; i < 16; ++i) det |= mu[i];
        const bool mask_i32 = ((det & 0xFFFFFF00u) == 0u);

        unsigned ewv;
        {
            const int rb = ((eb << 10) + row) << 10;
            const uint4 e0 = *((const uint4*)(edgep + rb) + ln);
            const uint4 e1 = *((const uint4*)(edgep + rb + 256) + ln);
            const uint4 e2 = *((const uint4*)(edgep + rb + 512) + ln);
            const uint4 e3 = *((const uint4*)(edgep + rb + 768) + ln);
            ewv = row_bits_i32<true>(e0, e1, e2, e3, ln);
        }
        const int pp = ((ln & 7) << 3) + (ln >> 3);
        #pragma unroll 2
        for (int bq = 0; bq < 16; ++bq) {
            const int bh = (bq << 2) + eb;
            unsigned u = ewv;
            if (!mask_i32) {
                const uint4 m = *((const uint4*)(maskp + ((size_t)((bh << 10) + row) << 10)) + ln);
                u |= pack_bytes_nz(m);
            } else {
                const int* mp = (const int*)maskp + ((size_t)((bh << 10) + row) << 10);
                const uint4 m0 = *((const uint4*)mp + ln);
                const uint4 m1 = *((const uint4*)(mp + 256) + ln);
                const uint4 m2 = *((const uint4*)(mp + 512) + ln);
                const uint4 m3 = *((const uint4*)(mp + 768) + ln);
                u |= row_bits_i32<false>(m0, m1, m2, m3, ln);
            }
            Mp[((size_t)((bh << 10) + row) << 6) + pp] = (ushort_t)u;
        }
    }
}

// Multi-tile main kernel: each block processes 4 consecutive rt slots of one bh,
// amortizing prologue/tail 4x. Per-rt body = R11's proven depth-2 rolling
// pipeline; attn store moved before the V phase so stores drain under PV MFMAs.
__global__ __launch_bounds__(512, 4)
void attn_main(const ushort_t* __restrict__ ws, float* __restrict__ outO,
               float* __restrict__ outA)
{
    __shared__ __align__(16) ushort_t p_lds[16 * 1024];   // 32 KB unnormalized P (swizzled)
    __shared__ float part[16][8];
    __shared__ float gred[16];
    __shared__ float opart[4][16][17];

    const ushort_t* Kp = ws;
    const ushort_t* Vp = ws + (1u << 22);
    const ushort_t* Qp = ws + (2u << 22);
    const ushort_t* Mp = ws + (3u << 22);

    const int tid = threadIdx.x, lane = tid & 63, w = tid >> 6;
    const int g = lane >> 4, ln = lane & 15;
    const int bid = blockIdx.x, xcd = bid & 7, slot = bid >> 3;   // 1024 blocks
    const int bh = xcd + ((slot >> 4) << 3);                      // 8 bh per xcd
    const int rt0 = (slot & 15) << 2;                             // 4 rt slots per block
    const int rw = (w << 4) + ln;
    const int ksw = rw & 7, vsw = ln & 7;
    const int dt = w & 3, kh = w >> 2;

    // rt-independent fragment source addresses
    const ushort_t* kbase = Kp + ((size_t)bh << 16) + (rw << 6);
    const int ko0 = (g ^ ksw) << 3, ko1 = ((4 + g) ^ ksw) << 3;
    const ushort_t* vrow = Vp + ((size_t)bh << 16) + (((dt << 4) + ln) << 7);
    const int vo0 = (((kh << 3) + g) ^ vsw) << 3, vo1 = (((kh << 3) + 4 + g) ^ vsw) << 3;

    #define LK(tt, oo) (*(const s16x8*)(kbase + ((tt) << 13) + (oo)))
    #define LV(tt, oo) (*(const s16x8*)(vrow  + ((tt) << 13) + (oo)))

    #pragma unroll 1
    for (int it = 0; it < 4; ++it) {
        const int rt = rt0 + it;
        const int r0 = rt << 4;

        // Q frags + mask bits for this rt
        const ushort_t* qs = Qp + ((size_t)((bh << 6) + rt) << 10) + (lane << 4);
        const s16x8 a0 = *(const s16x8*)(qs);
        const s16x8 a1 = *(const s16x8*)(qs + 8);
        uint4 br[4];
        #pragma unroll
        for (int reg = 0; reg < 4; ++reg)
            br[reg] = *(const uint4*)(Mp + ((size_t)((bh << 10) + r0 + (g << 2) + reg) << 6) + (w << 3));

        // rolling pipeline registers (depth 2)
        s16x8 kc0 = LK(0, ko0), kc1 = LK(0, ko1);
        s16x8 kn0 = LK(1, ko0), kn1 = LK(1, ko1);
        s16x8 va0, va1, vn0, vn1;

        float rs[4] = {0.f, 0.f, 0.f, 0.f};

        // ---- K phase: 8 tiles, depth-2 rolling prefetch ----
        #pragma unroll
        for (int kt = 0; kt < 8; ++kt) {
            const s16x8 b0 = kc0, b1 = kc1;
            kc0 = kn0; kc1 = kn1;
            if (kt < 6) {
                kn0 = LK(kt + 2, ko0); kn1 = LK(kt + 2, ko1);
            } else if (kt == 6) {
                va0 = LV(0, vo0); va1 = LV(0, vo1);
            } else {
                vn0 = LV(1, vo0); vn1 = LV(1, vo1);
            }

            f32x4 acc = {0.f, 0.f, 0.f, 0.f};
            acc = __builtin_amdgcn_mfma_f32_16x16x32_bf16(a0, b0, acc, 0, 0, 0);
            acc = __builtin_amdgcn_mfma_f32_16x16x32_bf16(a1, b1, acc, 0, 0, 0);

            #pragma unroll
            for (int reg = 0; reg < 4; ++reg) {
                const unsigned ew = selw(br[reg], kt >> 1);
                float sv = acc[reg];
                if ((ew >> (((kt & 1) << 4) + ln)) & 1u) sv = NEGV;
                const float e = __builtin_amdgcn_exp2f(sv);
                rs[reg] += e;
                const int prow = (g << 2) + reg;
                char* pd = (char*)p_lds + (prow << 11)
                         + ((((kt << 4) + (w << 1) + (ln >> 3)) ^ (prow & 7)) << 4)
                         + ((ln & 7) << 1);
                *(ushort_t*)pd = f2bf(e);
            }
        }

        // ---- row sums -> gred ----
        #pragma unroll
        for (int reg = 0; reg < 4; ++reg) {
            float s = rs[reg];
            s += __shfl_xor(s, 1);
            s += __shfl_xor(s, 2);
            s += __shfl_xor(s, 4);
            s += __shfl_xor(s, 8);
            if (ln == 0) part[(g << 2) + reg][w] = s;
        }
        __syncthreads();                          // B1: P + partials complete
        if (tid < 16) {
            float s = part[tid][0];
            #pragma unroll
            for (int i = 1; i < 8; ++i) s += part[tid][i];
            gred[tid] = __builtin_amdgcn_rcpf(s);
        }
        __syncthreads();                          // B2: gred visible

        // ---- attn -> global f32 BEFORE V phase: stores drain under PV MFMAs ----
        {
            const char* src = (const char*)p_lds;
            float* dstf = outA + ((size_t)((bh << 10) + r0) << 10);
            #pragma unroll
            for (int i = 0; i < 4; ++i) {
                const unsigned boff = (unsigned)((i * 512 + tid) << 4);
                const int rl = (int)(boff >> 11);
                const float rinv = gred[rl];
                const uint4 d4 = *(const uint4*)(src + (boff ^ ((rl & 7) << 4)));
                float4 f0, f1;
                f0.x = __builtin_bit_cast(float, d4.x << 16) * rinv;
                f0.y = __builtin_bit_cast(float, d4.x & 0xFFFF0000u) * rinv;
                f0.z = __builtin_bit_cast(float, d4.y << 16) * rinv;
                f0.w = __builtin_bit_cast(float, d4.y & 0xFFFF0000u) * rinv;
                f1.x = __builtin_bit_cast(float, d4.z << 16) * rinv;
                f1.y = __builtin_bit_cast(float, d4.z & 0xFFFF0000u) * rinv;
                f1.z = __builtin_bit_cast(float, d4.w << 16) * rinv;
                f1.w = __builtin_bit_cast(float, d4.w & 0xFFFF0000u) * rinv;
                char* db = (char*)dstf + ((size_t)boff << 1);
                *(float4*)db = f0;
                *(float4*)(db + 16) = f1;
            }
        }

        // ---- V phase: 8 tiles, depth-2 rolling prefetch ----
        f32x4 acco = {0.f, 0.f, 0.f, 0.f};
        #pragma unroll
        for (int ut = 0; ut < 8; ++ut) {
            const s16x8 b0 = va0, b1 = va1;
            va0 = vn0; va1 = vn1;
            if (ut < 6) {
                vn0 = LV(ut + 2, vo0); vn1 = LV(ut + 2, vo1);
            }
            const char* pl = (const char*)p_lds + (ln << 11);
            const s16x8 pa0 = *(const s16x8*)(pl + ((((ut << 4) + (kh << 3) + g)     ^ vsw) << 4));
            const s16x8 pa1 = *(const s16x8*)(pl + ((((ut << 4) + (kh << 3) + 4 + g) ^ vsw) << 4));
            acco = __builtin_amdgcn_mfma_f32_16x16x32_bf16(pa0, b0, acco, 0, 0, 0);
            acco = __builtin_amdgcn_mfma_f32_16x16x32_bf16(pa1, b1, acco, 0, 0, 0);
        }

        // ---- kh combine + O store ----
        if (kh == 1) {
            #pragma unroll
            for (int reg = 0; reg < 4; ++reg)
                opart[dt][(g << 2) + reg][ln] = acco[reg];
        }
        __syncthreads();                          // B3: opart visible; all p_lds reads done
        if (kh == 0) {
            #pragma unroll
            for (int reg = 0; reg < 4; ++reg) {
                const int rl = (g << 2) + reg;
                outO[((size_t)((bh << 10) + r0 + rl) << 6) + (dt << 4) + ln] =
                    (acco[reg] + opart[dt][rl][ln]) * gred[rl];
            }
        }
        // next iteration's K phase may now overwrite p_lds (post-B3)
    }
    #undef LK
    #undef LV
}

// -------- fallback (no workspace): direct-load version, correctness-only --------
__global__ __launch_bounds__(512)
void attn_fb(const float* __restrict__ qp, const float* __restrict__ kp,
             const float* __restrict__ vp, const unsigned char* __restrict__ maskp,
             const int* __restrict__ edgep, float* __restrict__ outO,
             float* __restrict__ outA)
{
    __shared__ __align__(16) ushort_t p_lds[16 * 1024];
    __shared__ float part[16][8];
    __shared__ float gred[16];
    __shared__ float opart[4][16][17];

    const int tid = threadIdx.x, lane = tid & 63, w = tid >> 6;
    const int g = lane >> 4, ln = lane & 15;
    const int bid = blockIdx.x, xcd = bid & 7, slot = bid >> 3;
    const int bh = xcd + ((slot >> 6) << 3);
    const int r0 = (slot & 63) << 4;
    const int c0 = w << 7;

    unsigned det = 0;
    const unsigned* mu = (const unsigned*)maskp;
    #pragma unroll
    for (int i = 0; i < 16; ++i) det |= mu[i];
    const bool mask_i32 = ((det & 0xFFFFFF00u) == 0u);

    const float* qb = qp + (((size_t)((bh << 10) + r0 + ln)) << 6) + (g << 3);
    s16x8 a0, a1;
    #pragma unroll
    for (int j = 0; j < 8; ++j) {
        a0[j] = (short)f2bf(qb[j] * QSCALE);
        a1[j] = (short)f2bf(qb[j + 32] * QSCALE);
    }

    f32x4 acc[8];
    #pragma unroll
    for (int nt = 0; nt < 8; ++nt) acc[nt] = (f32x4){0.f, 0.f, 0.f, 0.f};
    #pragma unroll
    for (int nt = 0; nt < 8; ++nt) {
        const float* kb = kp + (((size_t)((bh << 10) + c0 + (nt << 4) + ln)) << 6) + (g << 3);
        s16x8 b0, b1;
        #pragma unroll
        for (int j = 0; j < 8; ++j) {
            b0[j] = (short)f2bf(kb[j]);
            b1[j] = (short)f2bf(kb[j + 32]);
        }
        acc[nt] = __builtin_amdgcn_mfma_f32_16x16x32_bf16(a0, b0, acc[nt], 0, 0, 0);
        acc[nt] = __builtin_amdgcn_mfma_f32_16x16x32_bf16(a1, b1, acc[nt], 0, 0, 0);
    }

    float rs[4] = {0.f, 0.f, 0.f, 0.f};
    #pragma unroll
    for (int reg = 0; reg < 4; ++reg) {
        const int row = r0 + (g << 2) + reg;
        #pragma unroll
        for (int nt = 0; nt < 8; ++nt) {
            const int col = c0 + (nt << 4) + ln;
            float sv = acc[nt][reg];
            int mv;
            if (mask_i32) mv = ((const int*)maskp)[((size_t)((bh << 10) + row) << 10) + col];
            else          mv = (int)maskp[((size_t)((bh << 10) + row) << 10) + col];
            if (edgep[((size_t)((((bh & 3) << 10) + row)) << 10) + col] == 0 || mv != 0) sv = NEGV;
            const float e = __builtin_amdgcn_exp2f(sv);
            rs[reg] += e;
            const int rl = (g << 2) + reg;
            const unsigned off = ((unsigned)((rl << 11) | (col << 1))) ^ ((rl & 7) << 4);
            *(ushort_t*)((char*)p_lds + off) = f2bf(e);
        }
    }
    #pragma unroll
    for (int reg = 0; reg < 4; ++reg) {
        float s = rs[reg];
        s += __shfl_xor(s, 1);
        s += __shfl_xor(s, 2);
        s += __shfl_xor(s, 4);
        s += __shfl_xor(s, 8);
        if (ln == 0) part[(g << 2) + reg][w] = s;
    }
    __syncthreads();
    if (tid < 16) {
        float s = part[tid][0];
        #pragma unroll
        for (int i = 1; i < 8; ++i) s += part[tid][i];
        gred[tid] = __builtin_amdgcn_rcpf(s);
    }
    __syncthreads();

    const int dt = w & 3, kh = w >> 2;
    f32x4 acco = {0.f, 0.f, 0.f, 0.f};
    for (int kt = 0; kt < 16; ++kt) {
        const int ktg = (kh << 4) + kt;
        const unsigned offA = ((unsigned)((ln << 11) | (ktg << 6) | (g << 4))) ^ ((ln & 7) << 4);
        const s16x8 pa = *(const s16x8*)((const char*)p_lds + offA);
        s16x8 vb;
        #pragma unroll
        for (int j = 0; j < 8; ++j)
            vb[j] = (short)f2bf(vp[((size_t)((bh << 10) + (ktg << 5) + (g << 3) + j) << 6) + (dt << 4) + ln]);
        acco = __builtin_amdgcn_mfma_f32_16x16x32_bf16(pa, vb, acco, 0, 0, 0);
    }
    if (kh == 1) {
        #pragma unroll
        for (int reg = 0; reg < 4; ++reg)
            opart[dt][(g << 2) + reg][ln] = acco[reg];
    }
    __syncthreads();
    if (kh == 0) {
        #pragma unroll
        for (int reg = 0; reg < 4; ++reg) {
            const int rl = (g << 2) + reg;
            outO[((size_t)((bh << 10) + r0 + rl) << 6) + (dt << 4) + ln] =
                (acco[reg] + opart[dt][rl][ln]) * gred[rl];
        }
    }
    {
        const char* src = (const char*)p_lds;
        float* dstf = outA + ((size_t)((bh << 10) + r0) << 10);
        #pragma unroll
        for (int i = 0; i < 4; ++i) {
            const unsigned boff = (unsigned)((i * 512 + tid) << 4);
            const int rl = (int)(boff >> 11);
            const float rinv = gred[rl];
            const uint4 d4 = *(const uint4*)(src + (boff ^ ((rl & 7) << 4)));
            float4 f0, f1;
            f0.x = __builtin_bit_cast(float, d4.x << 16) * rinv;
            f0.y = __builtin_bit_cast(float, d4.x & 0xFFFF0000u) * rinv;
            f0.z = __builtin_bit_cast(float, d4.y << 16) * rinv;
            f0.w = __builtin_bit_cast(float, d4.y & 0xFFFF0000u) * rinv;
            f1.x = __builtin_bit_cast(float, d4.z << 16) * rinv;
            f1.y = __builtin_bit_cast(float, d4.z & 0xFFFF0000u) * rinv;
            f1.z = __builtin_bit_cast(float, d4.w << 16) * rinv;
            f1.w = __builtin_bit_cast(float, d4.w & 0xFFFF0000u) * rinv;
            char* db = (char*)dstf + ((size_t)boff << 1);
            *(float4*)db = f0;
            *(float4*)(db + 16) = f1;
        }
    }
}

extern "C" void kernel_launch(void* const* d_in, const int* in_sizes, int n_in,
                              void* d_out, int out_size, void* d_ws, size_t ws_size,
                              hipStream_t stream)
{
    (void)in_sizes; (void)n_in; (void)out_size;
    const float* qp = (const float*)d_in[0];
    const float* kp = (const float*)d_in[1];
    const float* vp = (const float*)d_in[2];
    const unsigned char* maskp = (const unsigned char*)d_in[3];
    const int* edgep = (const int*)d_in[4];

    float* outO = (float*)d_out;
    float* outA = outO + ((long long)BH_ * L_ * 64);       // outputs concat: output, attn

    const size_t need = (size_t)32 * 1024 * 1024;
    if (d_ws != nullptr && ws_size >= need) {
        ushort_t* ws = (ushort_t*)d_ws;
        prep<<<2112, 256, 0, stream>>>(qp, kp, vp, maskp, edgep, ws);
        attn_main<<<1024, 512, 0, stream>>>(ws, outO, outA);
    } else {
        attn_fb<<<4096, 512, 0, stream>>>(qp, kp, vp, maskp, edgep, outO, outA);
    }
}

// Round 13
// 218.409 us; speedup vs baseline: 1.7904x; 1.7904x over previous
//
#include <hip/hip_runtime.h>
#include <hip/hip_bf16.h>

#define L_ 1024
#define BH_ 64
#define NEGV (-1e15f)
#define QSCALE 0.18033688011112043f   // log2(e)/8: exp(S/8) == exp2(S*QSCALE)

typedef float f32x4 __attribute__((ext_vector_type(4)));
typedef short s16x8 __attribute__((ext_vector_type(8)));
typedef unsigned short ushort_t;

__device__ __forceinline__ unsigned short f2bf(float f) {
    return __builtin_bit_cast(unsigned short, __float2bfloat16(f));
}
__device__ __forceinline__ unsigned selw(uint4 v, int i) {
    switch (i) { case 0: return v.x; case 1: return v.y; case 2: return v.z; default: return v.w; }
}
__device__ __forceinline__ unsigned spread4(unsigned n) {   // bit j -> bit 4j
    return (n & 1u) | ((n & 2u) << 3) | ((n & 4u) << 6) | ((n & 8u) << 9);
}
__device__ __forceinline__ unsigned pack_bytes_nz(uint4 m) {
    unsigned u = 0;
    #pragma unroll
    for (int k = 0; k < 4; ++k) {
        const unsigned x = selw(m, k);
        u |= ((x & 0x000000FFu) ? 1u : 0u) << (k * 4 + 0);
        u |= ((x & 0x0000FF00u) ? 1u : 0u) << (k * 4 + 1);
        u |= ((x & 0x00FF0000u) ? 1u : 0u) << (k * 4 + 2);
        u |= ((x & 0xFF000000u) ? 1u : 0u) << (k * 4 + 3);
    }
    return u;
}

// 16-ballot transpose: row of 1024 i32 -> this lane's 16-col bit word.
template<bool TESTZERO>
__device__ __forceinline__ unsigned row_bits_i32(uint4 e0, uint4 e1, uint4 e2, uint4 e3, int ln)
{
    #define BAL_(v) (TESTZERO ? __ballot((v) == 0u) : __ballot((v) != 0u))
    const unsigned long long b00 = BAL_(e0.x), b01 = BAL_(e0.y), b02 = BAL_(e0.z), b03 = BAL_(e0.w);
    const unsigned long long b10 = BAL_(e1.x), b11 = BAL_(e1.y), b12 = BAL_(e1.z), b13 = BAL_(e1.w);
    const unsigned long long b20 = BAL_(e2.x), b21 = BAL_(e2.y), b22 = BAL_(e2.z), b23 = BAL_(e2.w);
    const unsigned long long b30 = BAL_(e3.x), b31 = BAL_(e3.y), b32 = BAL_(e3.z), b33 = BAL_(e3.w);
    #undef BAL_
    const int q0 = ln >> 4, sh = (ln & 15) << 2;
    unsigned u = 0;
    unsigned long long bp;
    bp = q0 == 0 ? b00 : q0 == 1 ? b10 : q0 == 2 ? b20 : b30;
    u |= spread4((unsigned)((bp >> sh) & 0xF)) << 0;
    bp = q0 == 0 ? b01 : q0 == 1 ? b11 : q0 == 2 ? b21 : b31;
    u |= spread4((unsigned)((bp >> sh) & 0xF)) << 1;
    bp = q0 == 0 ? b02 : q0 == 1 ? b12 : q0 == 2 ? b22 : b32;
    u |= spread4((unsigned)((bp >> sh) & 0xF)) << 2;
    bp = q0 == 0 ? b03 : q0 == 1 ? b13 : q0 == 2 ? b23 : b33;
    u |= spread4((unsigned)((bp >> sh) & 0xF)) << 3;
    return u;
}

// ws layout (ushort units): K' [0,4M), V' [4M,8M), Q' [8M,12M), mb [12M,16M)
// K': per (bh,kt) 8192 ushorts; row r(0..127)=128B, slot s holds d-chunk s^(r&7).
// V': per (bh,ut) 8192 ushorts; row d(0..63)=256B, slot p holds k-chunk p^(d&7).
// Q': per (bh,rt) 1024 ushorts; lane-record 32B, pre-scaled by QSCALE.
// mb: combined (edge==0 || mask) bits, [bh*1024+row][64 words], pp-permuted
//     so wave w's 8 kt-words are one uint4 at +w*8.
__global__ __launch_bounds__(256)
void prep(const float* __restrict__ qp, const float* __restrict__ kp,
          const float* __restrict__ vp, const unsigned char* __restrict__ maskp,
          const int* __restrict__ edgep, ushort_t* __restrict__ ws)
{
    __shared__ float tile[128][68];
    ushort_t* Kp = ws;
    ushort_t* Vp = ws + (1u << 22);
    ushort_t* Qp = ws + (2u << 22);
    ushort_t* Mp = ws + (3u << 22);

    const int b = blockIdx.x;
    const int t = threadIdx.x;

    if (b < 512) {
        // ---- K' ----
        const int bh = b >> 3, kt = b & 7;
        const int r = t >> 1, h = t & 1;
        const float* src = kp + (((size_t)((bh << 10) + (kt << 7) + r)) << 6) + (h << 5);
        float v[32];
        #pragma unroll
        for (int j = 0; j < 8; ++j) *(float4*)&v[j << 2] = *((const float4*)src + j);
        ushort_t* dst = Kp + ((size_t)((bh << 3) + kt) << 13) + (r << 6);
        #pragma unroll
        for (int q = 0; q < 4; ++q) {
            const int c = (h << 2) + q;
            const int s = c ^ (r & 7);
            s16x8 o;
            #pragma unroll
            for (int j = 0; j < 8; ++j) o[j] = (short)f2bf(v[(q << 3) + j]);
            *(s16x8*)(dst + (s << 3)) = o;
        }
    } else if (b < 1024) {
        // ---- V' (LDS-tiled transpose, both sides coalesced) ----
        const int idx = b - 512;
        const int bh = idx >> 3, vt = idx & 7;
        const float* vsrc = vp + (((size_t)(bh << 10) + (vt << 7)) << 6);
        #pragma unroll
        for (int i = 0; i < 8; ++i) {
            const int f4 = (i << 8) + t;
            const int k = f4 >> 4, d4 = f4 & 15;
            *(float4*)&tile[k][d4 << 2] = *((const float4*)vsrc + f4);
        }
        __syncthreads();
        ushort_t* dst = Vp + ((size_t)((bh << 3) + vt) << 13);
        #pragma unroll
        for (int i = 0; i < 4; ++i) {
            const int ci = (t << 2) + i;
            const int d = ci >> 4, p = ci & 15;
            const int c = p ^ (d & 7);
            s16x8 o;
            #pragma unroll
            for (int j = 0; j < 8; ++j) o[j] = (short)f2bf(tile[(c << 3) + j][d]);
            *(s16x8*)(dst + (ci << 3)) = o;
        }
    } else if (b < 1088) {
        // ---- Q' ----
        const int bh = b - 1024;
        const int wv = t >> 6, ln = t & 63;
        for (int i = 0; i < 16; ++i) {
            const int rt = (i << 2) + wv;
            const int r = (rt << 4) + (ln & 15), gq = ln >> 4;
            const float* src = qp + (((size_t)((bh << 10) + r)) << 6) + (gq << 3);
            const float4 q0 = *(const float4*)src;
            const float4 q1 = *(const float4*)(src + 4);
            const float4 q2 = *(const float4*)(src + 32);
            const float4 q3 = *(const float4*)(src + 36);
            s16x8 a, bfr;
            a[0]=(short)f2bf(q0.x*QSCALE); a[1]=(short)f2bf(q0.y*QSCALE);
            a[2]=(short)f2bf(q0.z*QSCALE); a[3]=(short)f2bf(q0.w*QSCALE);
            a[4]=(short)f2bf(q1.x*QSCALE); a[5]=(short)f2bf(q1.y*QSCALE);
            a[6]=(short)f2bf(q1.z*QSCALE); a[7]=(short)f2bf(q1.w*QSCALE);
            bfr[0]=(short)f2bf(q2.x*QSCALE); bfr[1]=(short)f2bf(q2.y*QSCALE);
            bfr[2]=(short)f2bf(q2.z*QSCALE); bfr[3]=(short)f2bf(q2.w*QSCALE);
            bfr[4]=(short)f2bf(q3.x*QSCALE); bfr[5]=(short)f2bf(q3.y*QSCALE);
            bfr[6]=(short)f2bf(q3.z*QSCALE); bfr[7]=(short)f2bf(q3.w*QSCALE);
            ushort_t* dst = Qp + ((size_t)((bh << 6) + rt) << 10) + (ln << 4);
            *(s16x8*)(dst) = a;
            *(s16x8*)(dst + 8) = bfr;
        }
    } else {
        // ---- mb: edge ballot once, OR mask bits per bh, single write ----
        const int wv = t >> 6, ln = t & 63;
        const int rid = ((b - 1088) << 2) + wv;   // 0..4095
        const int eb = rid >> 10, row = rid & 1023;

        unsigned det = 0;
        const unsigned* mu = (const unsigned*)maskp;
        #pragma unroll
        for (int i = 0; i < 16; ++i) det |= mu[i];
        const bool mask_i32 = ((det & 0xFFFFFF00u) == 0u);

        unsigned ewv;
        {
            const int rb = ((eb << 10) + row) << 10;
            const uint4 e0 = *((const uint4*)(edgep + rb) + ln);
            const uint4 e1 = *((const uint4*)(edgep + rb + 256) + ln);
            const uint4 e2 = *((const uint4*)(edgep + rb + 512) + ln);
            const uint4 e3 = *((const uint4*)(edgep + rb + 768) + ln);
            ewv = row_bits_i32<true>(e0, e1, e2, e3, ln);
        }
        const int pp = ((ln & 7) << 3) + (ln >> 3);
        #pragma unroll 2
        for (int bq = 0; bq < 16; ++bq) {
            const int bh = (bq << 2) + eb;
            unsigned u = ewv;
            if (!mask_i32) {
                const uint4 m = *((const uint4*)(maskp + ((size_t)((bh << 10) + row) << 10)) + ln);
                u |= pack_bytes_nz(m);
            } else {
                const int* mp = (const int*)maskp + ((size_t)((bh << 10) + row) << 10);
                const uint4 m0 = *((const uint4*)mp + ln);
                const uint4 m1 = *((const uint4*)(mp + 256) + ln);
                const uint4 m2 = *((const uint4*)(mp + 512) + ln);
                const uint4 m3 = *((const uint4*)(mp + 768) + ln);
                u |= row_bits_i32<false>(m0, m1, m2, m3, ln);
            }
            Mp[((size_t)((bh << 10) + row) << 6) + pp] = (ushort_t)u;
        }
    }
}

// Register-pipelined main kernel: explicit depth-2 rolling prefetch in NAMED
// registers (small live set -> no spill risk); no in-loop mask/global traffic
// beyond the prefetches; 3 __syncthreads total (rowsum x2, O-combine x1).
__global__ __launch_bounds__(512, 5)
void attn_main(const ushort_t* __restrict__ ws, float* __restrict__ outO,
               float* __restrict__ outA)
{
    __shared__ __align__(16) ushort_t p_lds[16 * 1024];   // 32 KB unnormalized P (swizzled)
    __shared__ float part[16][8];
    __shared__ float gred[16];
    __shared__ float opart[4][16][17];

    const ushort_t* Kp = ws;
    const ushort_t* Vp = ws + (1u << 22);
    const ushort_t* Qp = ws + (2u << 22);
    const ushort_t* Mp = ws + (3u << 22);

    const int tid = threadIdx.x, lane = tid & 63, w = tid >> 6;
    const int g = lane >> 4, ln = lane & 15;
    const int bid = blockIdx.x, xcd = bid & 7, slot = bid >> 3;
    const int bh = xcd + ((slot >> 6) << 3);
    const int rt = slot & 63;
    const int r0 = rt << 4;
    const int rw = (w << 4) + ln;
    const int ksw = rw & 7, vsw = ln & 7;
    const int dt = w & 3, kh = w >> 2;

    // Q frags (32B/lane direct)
    const ushort_t* qs = Qp + ((size_t)((bh << 6) + rt) << 10) + (lane << 4);
    const s16x8 a0 = *(const s16x8*)(qs);
    const s16x8 a1 = *(const s16x8*)(qs + 8);

    // combined mask bits: 4 uint4, whole K range
    uint4 br[4];
    #pragma unroll
    for (int reg = 0; reg < 4; ++reg)
        br[reg] = *(const uint4*)(Mp + ((size_t)((bh << 10) + r0 + (g << 2) + reg) << 6) + (w << 3));

    // fragment source addresses
    const ushort_t* kbase = Kp + ((size_t)bh << 16) + (rw << 6);
    const int ko0 = (g ^ ksw) << 3, ko1 = ((4 + g) ^ ksw) << 3;
    const ushort_t* vrow = Vp + ((size_t)bh << 16) + (((dt << 4) + ln) << 7);
    const int vo0 = (((kh << 3) + g) ^ vsw) << 3, vo1 = (((kh << 3) + 4 + g) ^ vsw) << 3;

    #define LK(tt, oo) (*(const s16x8*)(kbase + ((tt) << 13) + (oo)))
    #define LV(tt, oo) (*(const s16x8*)(vrow  + ((tt) << 13) + (oo)))

    // rolling pipeline registers (depth 2)
    s16x8 kc0 = LK(0, ko0), kc1 = LK(0, ko1);
    s16x8 kn0 = LK(1, ko0), kn1 = LK(1, ko1);
    s16x8 va0, va1, vn0, vn1;

    float rs[4] = {0.f, 0.f, 0.f, 0.f};

    // ================= K phase: 8 tiles, depth-2 rolling prefetch =================
    #pragma unroll
    for (int kt = 0; kt < 8; ++kt) {
        const s16x8 b0 = kc0, b1 = kc1;
        kc0 = kn0; kc1 = kn1;
        if (kt < 6) {
            kn0 = LK(kt + 2, ko0); kn1 = LK(kt + 2, ko1);
        } else if (kt == 6) {
            va0 = LV(0, vo0); va1 = LV(0, vo1);
        } else {
            vn0 = LV(1, vo0); vn1 = LV(1, vo1);
        }

        f32x4 acc = {0.f, 0.f, 0.f, 0.f};
        acc = __builtin_amdgcn_mfma_f32_16x16x32_bf16(a0, b0, acc, 0, 0, 0);
        acc = __builtin_amdgcn_mfma_f32_16x16x32_bf16(a1, b1, acc, 0, 0, 0);

        #pragma unroll
        for (int reg = 0; reg < 4; ++reg) {
            const unsigned ew = selw(br[reg], kt >> 1);
            float sv = acc[reg];
            if ((ew >> (((kt & 1) << 4) + ln)) & 1u) sv = NEGV;
            const float e = __builtin_amdgcn_exp2f(sv);
            rs[reg] += e;
            const int prow = (g << 2) + reg;
            char* pd = (char*)p_lds + (prow << 11)
                     + ((((kt << 4) + (w << 1) + (ln >> 3)) ^ (prow & 7)) << 4)
                     + ((ln & 7) << 1);
            *(ushort_t*)pd = f2bf(e);
        }
    }

    // ---- row sums -> gred ----
    #pragma unroll
    for (int reg = 0; reg < 4; ++reg) {
        float s = rs[reg];
        s += __shfl_xor(s, 1);
        s += __shfl_xor(s, 2);
        s += __shfl_xor(s, 4);
        s += __shfl_xor(s, 8);
        if (ln == 0) part[(g << 2) + reg][w] = s;
    }
    __syncthreads();                              // B1: P + partials complete
    if (tid < 16) {
        float s = part[tid][0];
        #pragma unroll
        for (int i = 1; i < 8; ++i) s += part[tid][i];
        gred[tid] = __builtin_amdgcn_rcpf(s);
    }
    __syncthreads();                              // B2: gred visible

    // ================= V phase: 8 tiles, depth-2 rolling prefetch =================
    f32x4 acco = {0.f, 0.f, 0.f, 0.f};
    #pragma unroll
    for (int ut = 0; ut < 8; ++ut) {
        const s16x8 b0 = va0, b1 = va1;
        va0 = vn0; va1 = vn1;
        if (ut < 6) {
            vn0 = LV(ut + 2, vo0); vn1 = LV(ut + 2, vo1);
        }
        const char* pl = (const char*)p_lds + (ln << 11);
        const s16x8 pa0 = *(const s16x8*)(pl + ((((ut << 4) + (kh << 3) + g)     ^ vsw) << 4));
        const s16x8 pa1 = *(const s16x8*)(pl + ((((ut << 4) + (kh << 3) + 4 + g) ^ vsw) << 4));
        acco = __builtin_amdgcn_mfma_f32_16x16x32_bf16(pa0, b0, acco, 0, 0, 0);
        acco = __builtin_amdgcn_mfma_f32_16x16x32_bf16(pa1, b1, acco, 0, 0, 0);
    }
    #undef LK
    #undef LV

    // ---- kh combine + O store ----
    if (kh == 1) {
        #pragma unroll
        for (int reg = 0; reg < 4; ++reg)
            opart[dt][(g << 2) + reg][ln] = acco[reg];
    }
    __syncthreads();                              // B3: opart visible
    if (kh == 0) {
        #pragma unroll
        for (int reg = 0; reg < 4; ++reg) {
            const int rl = (g << 2) + reg;
            outO[((size_t)((bh << 10) + r0 + rl) << 6) + (dt << 4) + ln] =
                (acco[reg] + opart[dt][rl][ln]) * gred[rl];
        }
    }

    // ---- attn -> global f32 (de-swizzle, widen, scale) ----
    {
        const char* src = (const char*)p_lds;
        float* dstf = outA + ((size_t)((bh << 10) + r0) << 10);
        #pragma unroll
        for (int i = 0; i < 4; ++i) {
            const unsigned boff = (unsigned)((i * 512 + tid) << 4);
            const int rl = (int)(boff >> 11);
            const float rinv = gred[rl];
            const uint4 d4 = *(const uint4*)(src + (boff ^ ((rl & 7) << 4)));
            float4 f0, f1;
            f0.x = __builtin_bit_cast(float, d4.x << 16) * rinv;
            f0.y = __builtin_bit_cast(float, d4.x & 0xFFFF0000u) * rinv;
            f0.z = __builtin_bit_cast(float, d4.y << 16) * rinv;
            f0.w = __builtin_bit_cast(float, d4.y & 0xFFFF0000u) * rinv;
            f1.x = __builtin_bit_cast(float, d4.z << 16) * rinv;
            f1.y = __builtin_bit_cast(float, d4.z & 0xFFFF0000u) * rinv;
            f1.z = __builtin_bit_cast(float, d4.w << 16) * rinv;
            f1.w = __builtin_bit_cast(float, d4.w & 0xFFFF0000u) * rinv;
            char* db = (char*)dstf + ((size_t)boff << 1);
            *(float4*)db = f0;
            *(float4*)(db + 16) = f1;
        }
    }
}

// -------- fallback (no workspace): direct-load version, correctness-only --------
__global__ __launch_bounds__(512)
void attn_fb(const float* __restrict__ qp, const float* __restrict__ kp,
             const float* __restrict__ vp, const unsigned char* __restrict__ maskp,
             const int* __restrict__ edgep, float* __restrict__ outO,
             float* __restrict__ outA)
{
    __shared__ __align__(16) ushort_t p_lds[16 * 1024];
    __shared__ float part[16][8];
    __shared__ float gred[16];
    __shared__ float opart[4][16][17];

    const int tid = threadIdx.x, lane = tid & 63, w = tid >> 6;
    const int g = lane >> 4, ln = lane & 15;
    const int bid = blockIdx.x, xcd = bid & 7, slot = bid >> 3;
    const int bh = xcd + ((slot >> 6) << 3);
    const int r0 = (slot & 63) << 4;
    const int c0 = w << 7;

    unsigned det = 0;
    const unsigned* mu = (const unsigned*)maskp;
    #pragma unroll
    for (int i = 0; i < 16; ++i) det |= mu[i];
    const bool mask_i32 = ((det & 0xFFFFFF00u) == 0u);

    const float* qb = qp + (((size_t)((bh << 10) + r0 + ln)) << 6) + (g << 3);
    s16x8 a0, a1;
    #pragma unroll
    for (int j = 0; j < 8; ++j) {
        a0[j] = (short)f2bf(qb[j] * QSCALE);
        a1[j] = (short)f2bf(qb[j + 32] * QSCALE);
    }

    f32x4 acc[8];
    #pragma unroll
    for (int nt = 0; nt < 8; ++nt) acc[nt] = (f32x4){0.f, 0.f, 0.f, 0.f};
    #pragma unroll
    for (int nt = 0; nt < 8; ++nt) {
        const float* kb = kp + (((size_t)((bh << 10) + c0 + (nt << 4) + ln)) << 6) + (g << 3);
        s16x8 b0, b1;
        #pragma unroll
        for (int j = 0; j < 8; ++j) {
            b0[j] = (short)f2bf(kb[j]);
            b1[j] = (short)f2bf(kb[j + 32]);
        }
        acc[nt] = __builtin_amdgcn_mfma_f32_16x16x32_bf16(a0, b0, acc[nt], 0, 0, 0);
        acc[nt] = __builtin_amdgcn_mfma_f32_16x16x32_bf16(a1, b1, acc[nt], 0, 0, 0);
    }

    float rs[4] = {0.f, 0.f, 0.f, 0.f};
    #pragma unroll
    for (int reg = 0; reg < 4; ++reg) {
        const int row = r0 + (g << 2) + reg;
        #pragma unroll
        for (int nt = 0; nt < 8; ++nt) {
            const int col = c0 + (nt << 4) + ln;
            float sv = acc[nt][reg];
            int mv;
            if (mask_i32) mv = ((const int*)maskp)[((size_t)((bh << 10) + row) << 10) + col];
            else          mv = (int)maskp[((size_t)((bh << 10) + row) << 10) + col];
            if (edgep[((size_t)((((bh & 3) << 10) + row)) << 10) + col] == 0 || mv != 0) sv = NEGV;
            const float e = __builtin_amdgcn_exp2f(sv);
            rs[reg] += e;
            const int rl = (g << 2) + reg;
            const unsigned off = ((unsigned)((rl << 11) | (col << 1))) ^ ((rl & 7) << 4);
            *(ushort_t*)((char*)p_lds + off) = f2bf(e);
        }
    }
    #pragma unroll
    for (int reg = 0; reg < 4; ++reg) {
        float s = rs[reg];
        s += __shfl_xor(s, 1);
        s += __shfl_xor(s, 2);
        s += __shfl_xor(s, 4);
        s += __shfl_xor(s, 8);
        if (ln == 0) part[(g << 2) + reg][w] = s;
    }
    __syncthreads();
    if (tid < 16) {
        float s = part[tid][0];
        #pragma unroll
        for (int i = 1; i < 8; ++i) s += part[tid][i];
        gred[tid] = __builtin_amdgcn_rcpf(s);
    }
    __syncthreads();

    const int dt = w & 3, kh = w >> 2;
    f32x4 acco = {0.f, 0.f, 0.f, 0.f};
    for (int kt = 0; kt < 16; ++kt) {
        const int ktg = (kh << 4) + kt;
        const unsigned offA = ((unsigned)((ln << 11) | (ktg << 6) | (g << 4))) ^ ((ln & 7) << 4);
        const s16x8 pa = *(const s16x8*)((const char*)p_lds + offA);
        s16x8 vb;
        #pragma unroll
        for (int j = 0; j < 8; ++j)
            vb[j] = (short)f2bf(vp[((size_t)((bh << 10) + (ktg << 5) + (g << 3) + j) << 6) + (dt << 4) + ln]);
        acco = __builtin_amdgcn_mfma_f32_16x16x32_bf16(pa, vb, acco, 0, 0, 0);
    }
    if (kh == 1) {
        #pragma unroll
        for (int reg = 0; reg < 4; ++reg)
            opart[dt][(g << 2) + reg][ln] = acco[reg];
    }
    __syncthreads();
    if (kh == 0) {
        #pragma unroll
        for (int reg = 0; reg < 4; ++reg) {
            const int rl = (g << 2) + reg;
            outO[((size_t)((bh << 10) + r0 + rl) << 6) + (dt << 4) + ln] =
                (acco[reg] + opart[dt][rl][ln]) * gred[rl];
        }
    }
    {
        const char* src = (const char*)p_lds;
        float* dstf = outA + ((size_t)((bh << 10) + r0) << 10);
        #pragma unroll
        for (int i = 0; i < 4; ++i) {
            const unsigned boff = (unsigned)((i * 512 + tid) << 4);
            const int rl = (int)(boff >> 11);
            const float rinv = gred[rl];
            const uint4 d4 = *(const uint4*)(src + (boff ^ ((rl & 7) << 4)));
            float4 f0, f1;
            f0.x = __builtin_bit_cast(float, d4.x << 16) * rinv;
            f0.y = __builtin_bit_cast(float, d4.x & 0xFFFF0000u) * rinv;
            f0.z = __builtin_bit_cast(float, d4.y << 16) * rinv;
            f0.w = __builtin_bit_cast(float, d4.y & 0xFFFF0000u) * rinv;
            f1.x = __builtin_bit_cast(float, d4.z << 16) * rinv;
            f1.y = __builtin_bit_cast(float, d4.z & 0xFFFF0000u) * rinv;
            f1.z = __builtin_bit_cast(float, d4.w << 16) * rinv;
            f1.w = __builtin_bit_cast(float, d4.w & 0xFFFF0000u) * rinv;
            char* db = (char*)dstf + ((size_t)boff << 1);
            *(float4*)db = f0;
            *(float4*)(db + 16) = f1;
        }
    }
}

extern "C" void kernel_launch(void* const* d_in, const int* in_sizes, int n_in,
                              void* d_out, int out_size, void* d_ws, size_t ws_size,
                              hipStream_t stream)
{
    (void)in_sizes; (void)n_in; (void)out_size;
    const float* qp = (const float*)d_in[0];
    const float* kp = (const float*)d_in[1];
    const float* vp = (const float*)d_in[2];
    const unsigned char* maskp = (const unsigned char*)d_in[3];
    const int* edgep = (const int*)d_in[4];

    float* outO = (float*)d_out;
    float* outA = outO + ((long long)BH_ * L_ * 64);       // outputs concat: output, attn

    const size_t need = (size_t)32 * 1024 * 1024;
    if (d_ws != nullptr && ws_size >= need) {
        ushort_t* ws = (ushort_t*)d_ws;
        prep<<<2112, 256, 0, stream>>>(qp, kp, vp, maskp, edgep, ws);
        attn_main<<<4096, 512, 0, stream>>>(ws, outO, outA);
    } else {
        attn_fb<<<4096, 512, 0, stream>>>(qp, kp, vp, maskp, edgep, outO, outA);
    }
}

// Round 14
// 216.242 us; speedup vs baseline: 1.8083x; 1.0100x over previous
//
#include <hip/hip_runtime.h>
#include <hip/hip_bf16.h>

#define L_ 1024
#define BH_ 64
#define NEGV (-1e15f)
#define QSCALE 0.18033688011112043f   // log2(e)/8: exp(S/8) == exp2(S*QSCALE)

typedef float f32x4 __attribute__((ext_vector_type(4)));
typedef short s16x8 __attribute__((ext_vector_type(8)));
typedef unsigned short ushort_t;

__device__ __forceinline__ unsigned short f2bf(float f) {
    return __builtin_bit_cast(unsigned short, __float2bfloat16(f));
}
__device__ __forceinline__ unsigned selw(uint4 v, int i) {
    switch (i) { case 0: return v.x; case 1: return v.y; case 2: return v.z; default: return v.w; }
}
__device__ __forceinline__ unsigned spread4(unsigned n) {   // bit j -> bit 4j
    return (n & 1u) | ((n & 2u) << 3) | ((n & 4u) << 6) | ((n & 8u) << 9);
}
__device__ __forceinline__ unsigned pack_bytes_nz(uint4 m) {
    unsigned u = 0;
    #pragma unroll
    for (int k = 0; k < 4; ++k) {
        const unsigned x = selw(m, k);
        u |= ((x & 0x000000FFu) ? 1u : 0u) << (k * 4 + 0);
        u |= ((x & 0x0000FF00u) ? 1u : 0u) << (k * 4 + 1);
        u |= ((x & 0x00FF0000u) ? 1u : 0u) << (k * 4 + 2);
        u |= ((x & 0xFF000000u) ? 1u : 0u) << (k * 4 + 3);
    }
    return u;
}

// 16-ballot transpose: row of 1024 i32 -> this lane's 16-col bit word.
template<bool TESTZERO>
__device__ __forceinline__ unsigned row_bits_i32(uint4 e0, uint4 e1, uint4 e2, uint4 e3, int ln)
{
    #define BAL_(v) (TESTZERO ? __ballot((v) == 0u) : __ballot((v) != 0u))
    const unsigned long long b00 = BAL_(e0.x), b01 = BAL_(e0.y), b02 = BAL_(e0.z), b03 = BAL_(e0.w);
    const unsigned long long b10 = BAL_(e1.x), b11 = BAL_(e1.y), b12 = BAL_(e1.z), b13 = BAL_(e1.w);
    const unsigned long long b20 = BAL_(e2.x), b21 = BAL_(e2.y), b22 = BAL_(e2.z), b23 = BAL_(e2.w);
    const unsigned long long b30 = BAL_(e3.x), b31 = BAL_(e3.y), b32 = BAL_(e3.z), b33 = BAL_(e3.w);
    #undef BAL_
    const int q0 = ln >> 4, sh = (ln & 15) << 2;
    unsigned u = 0;
    unsigned long long bp;
    bp = q0 == 0 ? b00 : q0 == 1 ? b10 : q0 == 2 ? b20 : b30;
    u |= spread4((unsigned)((bp >> sh) & 0xF)) << 0;
    bp = q0 == 0 ? b01 : q0 == 1 ? b11 : q0 == 2 ? b21 : b31;
    u |= spread4((unsigned)((bp >> sh) & 0xF)) << 1;
    bp = q0 == 0 ? b02 : q0 == 1 ? b12 : q0 == 2 ? b22 : b32;
    u |= spread4((unsigned)((bp >> sh) & 0xF)) << 2;
    bp = q0 == 0 ? b03 : q0 == 1 ? b13 : q0 == 2 ? b23 : b33;
    u |= spread4((unsigned)((bp >> sh) & 0xF)) << 3;
    return u;
}

// ws layout (ushort units): K' [0,4M), V' [4M,8M), Q' [8M,12M), mb [12M,16M)
// K': per (bh,kt) 8192 ushorts; row r(0..127)=128B, slot s holds d-chunk s^(r&7).
// V': per (bh,ut) 8192 ushorts; row d(0..63)=256B, slot p holds k-chunk p^(d&7).
// Q': per (bh,rt) 1024 ushorts; lane-record 32B, pre-scaled by QSCALE.
// mb: combined (edge==0 || mask) bits, [bh*1024+row][64 words], pp-permuted
//     so wave w's 8 kt-words are one uint4 at +w*8.
__global__ __launch_bounds__(256)
void prep(const float* __restrict__ qp, const float* __restrict__ kp,
          const float* __restrict__ vp, const unsigned char* __restrict__ maskp,
          const int* __restrict__ edgep, ushort_t* __restrict__ ws)
{
    __shared__ float tile[128][68];
    ushort_t* Kp = ws;
    ushort_t* Vp = ws + (1u << 22);
    ushort_t* Qp = ws + (2u << 22);
    ushort_t* Mp = ws + (3u << 22);

    const int b = blockIdx.x;
    const int t = threadIdx.x;

    if (b < 512) {
        // ---- K' ----
        const int bh = b >> 3, kt = b & 7;
        const int r = t >> 1, h = t & 1;
        const float* src = kp + (((size_t)((bh << 10) + (kt << 7) + r)) << 6) + (h << 5);
        float v[32];
        #pragma unroll
        for (int j = 0; j < 8; ++j) *(float4*)&v[j << 2] = *((const float4*)src + j);
        ushort_t* dst = Kp + ((size_t)((bh << 3) + kt) << 13) + (r << 6);
        #pragma unroll
        for (int q = 0; q < 4; ++q) {
            const int c = (h << 2) + q;
            const int s = c ^ (r & 7);
            s16x8 o;
            #pragma unroll
            for (int j = 0; j < 8; ++j) o[j] = (short)f2bf(v[(q << 3) + j]);
            *(s16x8*)(dst + (s << 3)) = o;
        }
    } else if (b < 1024) {
        // ---- V' (LDS-tiled transpose, both sides coalesced) ----
        const int idx = b - 512;
        const int bh = idx >> 3, vt = idx & 7;
        const float* vsrc = vp + (((size_t)(bh << 10) + (vt << 7)) << 6);
        #pragma unroll
        for (int i = 0; i < 8; ++i) {
            const int f4 = (i << 8) + t;
            const int k = f4 >> 4, d4 = f4 & 15;
            *(float4*)&tile[k][d4 << 2] = *((const float4*)vsrc + f4);
        }
        __syncthreads();
        ushort_t* dst = Vp + ((size_t)((bh << 3) + vt) << 13);
        #pragma unroll
        for (int i = 0; i < 4; ++i) {
            const int ci = (t << 2) + i;
            const int d = ci >> 4, p = ci & 15;
            const int c = p ^ (d & 7);
            s16x8 o;
            #pragma unroll
            for (int j = 0; j < 8; ++j) o[j] = (short)f2bf(tile[(c << 3) + j][d]);
            *(s16x8*)(dst + (ci << 3)) = o;
        }
    } else if (b < 1088) {
        // ---- Q' ----
        const int bh = b - 1024;
        const int wv = t >> 6, ln = t & 63;
        for (int i = 0; i < 16; ++i) {
            const int rt = (i << 2) + wv;
            const int r = (rt << 4) + (ln & 15), gq = ln >> 4;
            const float* src = qp + (((size_t)((bh << 10) + r)) << 6) + (gq << 3);
            const float4 q0 = *(const float4*)src;
            const float4 q1 = *(const float4*)(src + 4);
            const float4 q2 = *(const float4*)(src + 32);
            const float4 q3 = *(const float4*)(src + 36);
            s16x8 a, bfr;
            a[0]=(short)f2bf(q0.x*QSCALE); a[1]=(short)f2bf(q0.y*QSCALE);
            a[2]=(short)f2bf(q0.z*QSCALE); a[3]=(short)f2bf(q0.w*QSCALE);
            a[4]=(short)f2bf(q1.x*QSCALE); a[5]=(short)f2bf(q1.y*QSCALE);
            a[6]=(short)f2bf(q1.z*QSCALE); a[7]=(short)f2bf(q1.w*QSCALE);
            bfr[0]=(short)f2bf(q2.x*QSCALE); bfr[1]=(short)f2bf(q2.y*QSCALE);
            bfr[2]=(short)f2bf(q2.z*QSCALE); bfr[3]=(short)f2bf(q2.w*QSCALE);
            bfr[4]=(short)f2bf(q3.x*QSCALE); bfr[5]=(short)f2bf(q3.y*QSCALE);
            bfr[6]=(short)f2bf(q3.z*QSCALE); bfr[7]=(short)f2bf(q3.w*QSCALE);
            ushort_t* dst = Qp + ((size_t)((bh << 6) + rt) << 10) + (ln << 4);
            *(s16x8*)(dst) = a;
            *(s16x8*)(dst + 8) = bfr;
        }
    } else {
        // ---- mb: ONE row per block; 4 waves split the 16 bh (4 each).
        //      Edge ballot recomputed per wave (same 4KB row -> L1-hot). ----
        const int wv = t >> 6, ln = t & 63;
        const int rid = b - 1088;                 // 0..4095
        const int eb = rid >> 10, row = rid & 1023;

        unsigned det = 0;
        const unsigned* mu = (const unsigned*)maskp;
        #pragma unroll
        for (int i = 0; i < 16; ++i) det |= mu[i];
        const bool mask_i32 = ((det & 0xFFFFFF00u) == 0u);

        unsigned ewv;
        {
            const int rb = ((eb << 10) + row) << 10;
            const uint4 e0 = *((const uint4*)(edgep + rb) + ln);
            const uint4 e1 = *((const uint4*)(edgep + rb + 256) + ln);
            const uint4 e2 = *((const uint4*)(edgep + rb + 512) + ln);
            const uint4 e3 = *((const uint4*)(edgep + rb + 768) + ln);
            ewv = row_bits_i32<true>(e0, e1, e2, e3, ln);
        }
        const int pp = ((ln & 7) << 3) + (ln >> 3);
        #pragma unroll
        for (int i = 0; i < 4; ++i) {
            const int bq = (wv << 2) + i;          // this wave's 4 of 16 bh
            const int bh = (bq << 2) + eb;
            unsigned u = ewv;
            if (!mask_i32) {
                const uint4 m = *((const uint4*)(maskp + ((size_t)((bh << 10) + row) << 10)) + ln);
                u |= pack_bytes_nz(m);
            } else {
                const int* mp = (const int*)maskp + ((size_t)((bh << 10) + row) << 10);
                const uint4 m0 = *((const uint4*)mp + ln);
                const uint4 m1 = *((const uint4*)(mp + 256) + ln);
                const uint4 m2 = *((const uint4*)(mp + 512) + ln);
                const uint4 m3 = *((const uint4*)(mp + 768) + ln);
                u |= row_bits_i32<false>(m0, m1, m2, m3, ln);
            }
            Mp[((size_t)((bh << 10) + row) << 6) + pp] = (ushort_t)u;
        }
    }
}

// Register-pipelined main kernel: explicit depth-2 rolling prefetch in NAMED
// registers (small live set -> no spill risk); no in-loop mask/global traffic
// beyond the prefetches; 3 __syncthreads total (rowsum x2, O-combine x1).
// NOTE: byte-identical to the proven 218-220us R9/R11/R13 version. Do not
// restructure (R10/R12 both regressed 1.5-2x on any reordering).
__global__ __launch_bounds__(512, 5)
void attn_main(const ushort_t* __restrict__ ws, float* __restrict__ outO,
               float* __restrict__ outA)
{
    __shared__ __align__(16) ushort_t p_lds[16 * 1024];   // 32 KB unnormalized P (swizzled)
    __shared__ float part[16][8];
    __shared__ float gred[16];
    __shared__ float opart[4][16][17];

    const ushort_t* Kp = ws;
    const ushort_t* Vp = ws + (1u << 22);
    const ushort_t* Qp = ws + (2u << 22);
    const ushort_t* Mp = ws + (3u << 22);

    const int tid = threadIdx.x, lane = tid & 63, w = tid >> 6;
    const int g = lane >> 4, ln = lane & 15;
    const int bid = blockIdx.x, xcd = bid & 7, slot = bid >> 3;
    const int bh = xcd + ((slot >> 6) << 3);
    const int rt = slot & 63;
    const int r0 = rt << 4;
    const int rw = (w << 4) + ln;
    const int ksw = rw & 7, vsw = ln & 7;
    const int dt = w & 3, kh = w >> 2;

    // Q frags (32B/lane direct)
    const ushort_t* qs = Qp + ((size_t)((bh << 6) + rt) << 10) + (lane << 4);
    const s16x8 a0 = *(const s16x8*)(qs);
    const s16x8 a1 = *(const s16x8*)(qs + 8);

    // combined mask bits: 4 uint4, whole K range
    uint4 br[4];
    #pragma unroll
    for (int reg = 0; reg < 4; ++reg)
        br[reg] = *(const uint4*)(Mp + ((size_t)((bh << 10) + r0 + (g << 2) + reg) << 6) + (w << 3));

    // fragment source addresses
    const ushort_t* kbase = Kp + ((size_t)bh << 16) + (rw << 6);
    const int ko0 = (g ^ ksw) << 3, ko1 = ((4 + g) ^ ksw) << 3;
    const ushort_t* vrow = Vp + ((size_t)bh << 16) + (((dt << 4) + ln) << 7);
    const int vo0 = (((kh << 3) + g) ^ vsw) << 3, vo1 = (((kh << 3) + 4 + g) ^ vsw) << 3;

    #define LK(tt, oo) (*(const s16x8*)(kbase + ((tt) << 13) + (oo)))
    #define LV(tt, oo) (*(const s16x8*)(vrow  + ((tt) << 13) + (oo)))

    // rolling pipeline registers (depth 2)
    s16x8 kc0 = LK(0, ko0), kc1 = LK(0, ko1);
    s16x8 kn0 = LK(1, ko0), kn1 = LK(1, ko1);
    s16x8 va0, va1, vn0, vn1;

    float rs[4] = {0.f, 0.f, 0.f, 0.f};

    // ================= K phase: 8 tiles, depth-2 rolling prefetch =================
    #pragma unroll
    for (int kt = 0; kt < 8; ++kt) {
        const s16x8 b0 = kc0, b1 = kc1;
        kc0 = kn0; kc1 = kn1;
        if (kt < 6) {
            kn0 = LK(kt + 2, ko0); kn1 = LK(kt + 2, ko1);
        } else if (kt == 6) {
            va0 = LV(0, vo0); va1 = LV(0, vo1);
        } else {
            vn0 = LV(1, vo0); vn1 = LV(1, vo1);
        }

        f32x4 acc = {0.f, 0.f, 0.f, 0.f};
        acc = __builtin_amdgcn_mfma_f32_16x16x32_bf16(a0, b0, acc, 0, 0, 0);
        acc = __builtin_amdgcn_mfma_f32_16x16x32_bf16(a1, b1, acc, 0, 0, 0);

        #pragma unroll
        for (int reg = 0; reg < 4; ++reg) {
            const unsigned ew = selw(br[reg], kt >> 1);
            float sv = acc[reg];
            if ((ew >> (((kt & 1) << 4) + ln)) & 1u) sv = NEGV;
            const float e = __builtin_amdgcn_exp2f(sv);
            rs[reg] += e;
            const int prow = (g << 2) + reg;
            char* pd = (char*)p_lds + (prow << 11)
                     + ((((kt << 4) + (w << 1) + (ln >> 3)) ^ (prow & 7)) << 4)
                     + ((ln & 7) << 1);
            *(ushort_t*)pd = f2bf(e);
        }
    }

    // ---- row sums -> gred ----
    #pragma unroll
    for (int reg = 0; reg < 4; ++reg) {
        float s = rs[reg];
        s += __shfl_xor(s, 1);
        s += __shfl_xor(s, 2);
        s += __shfl_xor(s, 4);
        s += __shfl_xor(s, 8);
        if (ln == 0) part[(g << 2) + reg][w] = s;
    }
    __syncthreads();                              // B1: P + partials complete
    if (tid < 16) {
        float s = part[tid][0];
        #pragma unroll
        for (int i = 1; i < 8; ++i) s += part[tid][i];
        gred[tid] = __builtin_amdgcn_rcpf(s);
    }
    __syncthreads();                              // B2: gred visible

    // ================= V phase: 8 tiles, depth-2 rolling prefetch =================
    f32x4 acco = {0.f, 0.f, 0.f, 0.f};
    #pragma unroll
    for (int ut = 0; ut < 8; ++ut) {
        const s16x8 b0 = va0, b1 = va1;
        va0 = vn0; va1 = vn1;
        if (ut < 6) {
            vn0 = LV(ut + 2, vo0); vn1 = LV(ut + 2, vo1);
        }
        const char* pl = (const char*)p_lds + (ln << 11);
        const s16x8 pa0 = *(const s16x8*)(pl + ((((ut << 4) + (kh << 3) + g)     ^ vsw) << 4));
        const s16x8 pa1 = *(const s16x8*)(pl + ((((ut << 4) + (kh << 3) + 4 + g) ^ vsw) << 4));
        acco = __builtin_amdgcn_mfma_f32_16x16x32_bf16(pa0, b0, acco, 0, 0, 0);
        acco = __builtin_amdgcn_mfma_f32_16x16x32_bf16(pa1, b1, acco, 0, 0, 0);
    }
    #undef LK
    #undef LV

    // ---- kh combine + O store ----
    if (kh == 1) {
        #pragma unroll
        for (int reg = 0; reg < 4; ++reg)
            opart[dt][(g << 2) + reg][ln] = acco[reg];
    }
    __syncthreads();                              // B3: opart visible
    if (kh == 0) {
        #pragma unroll
        for (int reg = 0; reg < 4; ++reg) {
            const int rl = (g << 2) + reg;
            outO[((size_t)((bh << 10) + r0 + rl) << 6) + (dt << 4) + ln] =
                (acco[reg] + opart[dt][rl][ln]) * gred[rl];
        }
    }

    // ---- attn -> global f32 (de-swizzle, widen, scale) ----
    {
        const char* src = (const char*)p_lds;
        float* dstf = outA + ((size_t)((bh << 10) + r0) << 10);
        #pragma unroll
        for (int i = 0; i < 4; ++i) {
            const unsigned boff = (unsigned)((i * 512 + tid) << 4);
            const int rl = (int)(boff >> 11);
            const float rinv = gred[rl];
            const uint4 d4 = *(const uint4*)(src + (boff ^ ((rl & 7) << 4)));
            float4 f0, f1;
            f0.x = __builtin_bit_cast(float, d4.x << 16) * rinv;
            f0.y = __builtin_bit_cast(float, d4.x & 0xFFFF0000u) * rinv;
            f0.z = __builtin_bit_cast(float, d4.y << 16) * rinv;
            f0.w = __builtin_bit_cast(float, d4.y & 0xFFFF0000u) * rinv;
            f1.x = __builtin_bit_cast(float, d4.z << 16) * rinv;
            f1.y = __builtin_bit_cast(float, d4.z & 0xFFFF0000u) * rinv;
            f1.z = __builtin_bit_cast(float, d4.w << 16) * rinv;
            f1.w = __builtin_bit_cast(float, d4.w & 0xFFFF0000u) * rinv;
            char* db = (char*)dstf + ((size_t)boff << 1);
            *(float4*)db = f0;
            *(float4*)(db + 16) = f1;
        }
    }
}

// -------- fallback (no workspace): direct-load version, correctness-only --------
__global__ __launch_bounds__(512)
void attn_fb(const float* __restrict__ qp, const float* __restrict__ kp,
             const float* __restrict__ vp, const unsigned char* __restrict__ maskp,
             const int* __restrict__ edgep, float* __restrict__ outO,
             float* __restrict__ outA)
{
    __shared__ __align__(16) ushort_t p_lds[16 * 1024];
    __shared__ float part[16][8];
    __shared__ float gred[16];
    __shared__ float opart[4][16][17];

    const int tid = threadIdx.x, lane = tid & 63, w = tid >> 6;
    const int g = lane >> 4, ln = lane & 15;
    const int bid = blockIdx.x, xcd = bid & 7, slot = bid >> 3;
    const int bh = xcd + ((slot >> 6) << 3);
    const int r0 = (slot & 63) << 4;
    const int c0 = w << 7;

    unsigned det = 0;
    const unsigned* mu = (const unsigned*)maskp;
    #pragma unroll
    for (int i = 0; i < 16; ++i) det |= mu[i];
    const bool mask_i32 = ((det & 0xFFFFFF00u) == 0u);

    const float* qb = qp + (((size_t)((bh << 10) + r0 + ln)) << 6) + (g << 3);
    s16x8 a0, a1;
    #pragma unroll
    for (int j = 0; j < 8; ++j) {
        a0[j] = (short)f2bf(qb[j] * QSCALE);
        a1[j] = (short)f2bf(qb[j + 32] * QSCALE);
    }

    f32x4 acc[8];
    #pragma unroll
    for (int nt = 0; nt < 8; ++nt) acc[nt] = (f32x4){0.f, 0.f, 0.f, 0.f};
    #pragma unroll
    for (int nt = 0; nt < 8; ++nt) {
        const float* kb = kp + (((size_t)((bh << 10) + c0 + (nt << 4) + ln)) << 6) + (g << 3);
        s16x8 b0, b1;
        #pragma unroll
        for (int j = 0; j < 8; ++j) {
            b0[j] = (short)f2bf(kb[j]);
            b1[j] = (short)f2bf(kb[j + 32]);
        }
        acc[nt] = __builtin_amdgcn_mfma_f32_16x16x32_bf16(a0, b0, acc[nt], 0, 0, 0);
        acc[nt] = __builtin_amdgcn_mfma_f32_16x16x32_bf16(a1, b1, acc[nt], 0, 0, 0);
    }

    float rs[4] = {0.f, 0.f, 0.f, 0.f};
    #pragma unroll
    for (int reg = 0; reg < 4; ++reg) {
        const int row = r0 + (g << 2) + reg;
        #pragma unroll
        for (int nt = 0; nt < 8; ++nt) {
            const int col = c0 + (nt << 4) + ln;
            float sv = acc[nt][reg];
            int mv;
            if (mask_i32) mv = ((const int*)maskp)[((size_t)((bh << 10) + row) << 10) + col];
            else          mv = (int)maskp[((size_t)((bh << 10) + row) << 10) + col];
            if (edgep[((size_t)((((bh & 3) << 10) + row)) << 10) + col] == 0 || mv != 0) sv = NEGV;
            const float e = __builtin_amdgcn_exp2f(sv);
            rs[reg] += e;
            const int rl = (g << 2) + reg;
            const unsigned off = ((unsigned)((rl << 11) | (col << 1))) ^ ((rl & 7) << 4);
            *(ushort_t*)((char*)p_lds + off) = f2bf(e);
        }
    }
    #pragma unroll
    for (int reg = 0; reg < 4; ++reg) {
        float s = rs[reg];
        s += __shfl_xor(s, 1);
        s += __shfl_xor(s, 2);
        s += __shfl_xor(s, 4);
        s += __shfl_xor(s, 8);
        if (ln == 0) part[(g << 2) + reg][w] = s;
    }
    __syncthreads();
    if (tid < 16) {
        float s = part[tid][0];
        #pragma unroll
        for (int i = 1; i < 8; ++i) s += part[tid][i];
        gred[tid] = __builtin_amdgcn_rcpf(s);
    }
    __syncthreads();

    const int dt = w & 3, kh = w >> 2;
    f32x4 acco = {0.f, 0.f, 0.f, 0.f};
    for (int kt = 0; kt < 16; ++kt) {
        const int ktg = (kh << 4) + kt;
        const unsigned offA = ((unsigned)((ln << 11) | (ktg << 6) | (g << 4))) ^ ((ln & 7) << 4);
        const s16x8 pa = *(const s16x8*)((const char*)p_lds + offA);
        s16x8 vb;
        #pragma unroll
        for (int j = 0; j < 8; ++j)
            vb[j] = (short)f2bf(vp[((size_t)((bh << 10) + (ktg << 5) + (g << 3) + j) << 6) + (dt << 4) + ln]);
        acco = __builtin_amdgcn_mfma_f32_16x16x32_bf16(pa, vb, acco, 0, 0, 0);
    }
    if (kh == 1) {
        #pragma unroll
        for (int reg = 0; reg < 4; ++reg)
            opart[dt][(g << 2) + reg][ln] = acco[reg];
    }
    __syncthreads();
    if (kh == 0) {
        #pragma unroll
        for (int reg = 0; reg < 4; ++reg) {
            const int rl = (g << 2) + reg;
            outO[((size_t)((bh << 10) + r0 + rl) << 6) + (dt << 4) + ln] =
                (acco[reg] + opart[dt][rl][ln]) * gred[rl];
        }
    }
    {
        const char* src = (const char*)p_lds;
        float* dstf = outA + ((size_t)((bh << 10) + r0) << 10);
        #pragma unroll
        for (int i = 0; i < 4; ++i) {
            const unsigned boff = (unsigned)((i * 512 + tid) << 4);
            const int rl = (int)(boff >> 11);
            const float rinv = gred[rl];
            const uint4 d4 = *(const uint4*)(src + (boff ^ ((rl & 7) << 4)));
            float4 f0, f1;
            f0.x = __builtin_bit_cast(float, d4.x << 16) * rinv;
            f0.y = __builtin_bit_cast(float, d4.x & 0xFFFF0000u) * rinv;
            f0.z = __builtin_bit_cast(float, d4.y << 16) * rinv;
            f0.w = __builtin_bit_cast(float, d4.y & 0xFFFF0000u) * rinv;
            f1.x = __builtin_bit_cast(float, d4.z << 16) * rinv;
            f1.y = __builtin_bit_cast(float, d4.z & 0xFFFF0000u) * rinv;
            f1.z = __builtin_bit_cast(float, d4.w << 16) * rinv;
            f1.w = __builtin_bit_cast(float, d4.w & 0xFFFF0000u) * rinv;
            char* db = (char*)dstf + ((size_t)boff << 1);
            *(float4*)db = f0;
            *(float4*)(db + 16) = f1;
        }
    }
}

extern "C" void kernel_launch(void* const* d_in, const int* in_sizes, int n_in,
                              void* d_out, int out_size, void* d_ws, size_t ws_size,
                              hipStream_t stream)
{
    (void)in_sizes; (void)n_in; (void)out_size;
    const float* qp = (const float*)d_in[0];
    const float* kp = (const float*)d_in[1];
    const float* vp = (const float*)d_in[2];
    const unsigned char* maskp = (const unsigned char*)d_in[3];
    const int* edgep = (const int*)d_in[4];

    float* outO = (float*)d_out;
    float* outA = outO + ((long long)BH_ * L_ * 64);       // outputs concat: output, attn

    const size_t need = (size_t)32 * 1024 * 1024;
    if (d_ws != nullptr && ws_size >= need) {
        ushort_t* ws = (ushort_t*)d_ws;
        prep<<<5184, 256, 0, stream>>>(qp, kp, vp, maskp, edgep, ws);
        attn_main<<<4096, 512, 0, stream>>>(ws, outO, outA);
    } else {
        attn_fb<<<4096, 512, 0, stream>>>(qp, kp, vp, maskp, edgep, outO, outA);
    }
}